// Round 3
// baseline (358.264 us; speedup 1.0000x reference)
//
#include <hip/hip_runtime.h>
#include <math.h>

#define EMB 768
#define HS 64
#define SEQ 2048
#define NB 8
#define NROWS (NB * SEQ)

// ---------------- Kernel 1: QKV projection ----------------
// grid = NROWS/64 = 256 blocks, 256 threads.
// Per block: 64 x-rows times all 192 output cols (Q|K|V), K-chunks of 64.
__global__ __launch_bounds__(256) void qkv_kernel(
    const float* __restrict__ x,
    const float* __restrict__ Wq,
    const float* __restrict__ Wk,
    const float* __restrict__ Wv,
    float* __restrict__ qo, float* __restrict__ ko, float* __restrict__ vo)
{
    __shared__ float xs[64][64];    // [kk][m]  (x transposed)
    __shared__ float ws[64][192];   // [kk][ Q(0..63) | K(64..127) | V(128..191) ]

    const int tid  = threadIdx.x;
    const int row0 = blockIdx.x * 64;
    const int a = tid >> 4;          // row group: rows 4a..4a+3
    const int b = tid & 15;          // col group: cols 4b..4b+3 (per matrix)
    const int xm0 = (tid & 15) * 4;  // staging: 4x4 transpose chunk
    const int xk0 = (tid >> 4) * 4;

    float acc[3][4][4];
#pragma unroll
    for (int m = 0; m < 3; ++m)
#pragma unroll
        for (int r = 0; r < 4; ++r)
#pragma unroll
            for (int c = 0; c < 4; ++c) acc[m][r][c] = 0.f;

    for (int kc = 0; kc < EMB; kc += 64) {
        // -- global loads to registers (no LDS touch yet) --
        float4 xr[4];
#pragma unroll
        for (int i = 0; i < 4; ++i)
            xr[i] = *(const float4*)&x[(size_t)(row0 + xm0 + i) * EMB + kc + xk0];
        float4 wqr[4], wkr[4], wvr[4];
#pragma unroll
        for (int t = 0; t < 4; ++t) {
            int idx = tid + t * 256;
            int kk = idx >> 4, j4 = (idx & 15) * 4;
            wqr[t] = *(const float4*)&Wq[(size_t)(kc + kk) * HS + j4];
            wkr[t] = *(const float4*)&Wk[(size_t)(kc + kk) * HS + j4];
            wvr[t] = *(const float4*)&Wv[(size_t)(kc + kk) * HS + j4];
        }
        __syncthreads();   // previous chunk's compute reads done
        // -- LDS stores --
        *(float4*)&xs[xk0 + 0][xm0] = make_float4(xr[0].x, xr[1].x, xr[2].x, xr[3].x);
        *(float4*)&xs[xk0 + 1][xm0] = make_float4(xr[0].y, xr[1].y, xr[2].y, xr[3].y);
        *(float4*)&xs[xk0 + 2][xm0] = make_float4(xr[0].z, xr[1].z, xr[2].z, xr[3].z);
        *(float4*)&xs[xk0 + 3][xm0] = make_float4(xr[0].w, xr[1].w, xr[2].w, xr[3].w);
#pragma unroll
        for (int t = 0; t < 4; ++t) {
            int idx = tid + t * 256;
            int kk = idx >> 4, j4 = (idx & 15) * 4;
            *(float4*)&ws[kk][j4]       = wqr[t];
            *(float4*)&ws[kk][64 + j4]  = wkr[t];
            *(float4*)&ws[kk][128 + j4] = wvr[t];
        }
        __syncthreads();
        // -- compute: 48 FMA per 4 b128 LDS reads --
#pragma unroll 8
        for (int kk = 0; kk < 64; ++kk) {
            float4 xv  = *(const float4*)&xs[kk][4 * a];
            float4 wq4 = *(const float4*)&ws[kk][4 * b];
            float4 wk4 = *(const float4*)&ws[kk][64 + 4 * b];
            float4 wv4 = *(const float4*)&ws[kk][128 + 4 * b];
            float xa[4] = {xv.x, xv.y, xv.z, xv.w};
            float wa[3][4] = {{wq4.x, wq4.y, wq4.z, wq4.w},
                              {wk4.x, wk4.y, wk4.z, wk4.w},
                              {wv4.x, wv4.y, wv4.z, wv4.w}};
#pragma unroll
            for (int m = 0; m < 3; ++m)
#pragma unroll
                for (int r = 0; r < 4; ++r)
#pragma unroll
                    for (int c = 0; c < 4; ++c)
                        acc[m][r][c] = fmaf(xa[r], wa[m][c], acc[m][r][c]);
        }
    }
    // -- write Q,K,V --
#pragma unroll
    for (int r = 0; r < 4; ++r) {
        size_t row = (size_t)(row0 + 4 * a + r);
        *(float4*)&qo[row * HS + 4 * b] =
            make_float4(acc[0][r][0], acc[0][r][1], acc[0][r][2], acc[0][r][3]);
        *(float4*)&ko[row * HS + 4 * b] =
            make_float4(acc[1][r][0], acc[1][r][1], acc[1][r][2], acc[1][r][3]);
        *(float4*)&vo[row * HS + 4 * b] =
            make_float4(acc[2][r][0], acc[2][r][1], acc[2][r][2], acc[2][r][3]);
    }
}

// ---------------- Kernel 2: causal flash attention ----------------
// grid = NB * (SEQ/32) = 512 blocks, 256 threads. BQ=32 query rows/block,
// KBLK=64. Heavy q-tiles launched first for load balance.
__global__ __launch_bounds__(256) void attn_kernel(
    const float* __restrict__ q, const float* __restrict__ k,
    const float* __restrict__ v, float* __restrict__ out)
{
    __shared__ float Qt[64][32];   // [e][r], pre-scaled by 1/8
    __shared__ float Kt[64][64];   // [e][c]
    __shared__ float Vs[64][64];   // [c][h]
    __shared__ float Ps[64][34];   // [c][r] (+2 pad: bank spread, keeps 8B align)

    const int tid   = threadIdx.x;
    const int bid   = blockIdx.x;
    const int batch = bid & 7;
    const int qi    = 63 - (bid >> 3);      // descending work
    const int nk    = (qi >> 1) + 1;        // # 64-wide k-tiles
    const size_t base = (size_t)batch * SEQ * HS;
    const int qrow0 = qi * 32;
    const int a = tid >> 4;                 // rows 2a, 2a+1
    const int b = tid & 15;                 // cols 4b..4b+3

    // stage Q transposed + scaled (4x4 register transposes, 128 threads)
    if (tid < 128) {
        int m0 = (tid & 7) * 4;
        int e0 = (tid >> 3) * 4;
        float4 r[4];
#pragma unroll
        for (int i = 0; i < 4; ++i) {
            r[i] = *(const float4*)&q[base + (size_t)(qrow0 + m0 + i) * HS + e0];
            r[i].x *= 0.125f; r[i].y *= 0.125f; r[i].z *= 0.125f; r[i].w *= 0.125f;
        }
        *(float4*)&Qt[e0 + 0][m0] = make_float4(r[0].x, r[1].x, r[2].x, r[3].x);
        *(float4*)&Qt[e0 + 1][m0] = make_float4(r[0].y, r[1].y, r[2].y, r[3].y);
        *(float4*)&Qt[e0 + 2][m0] = make_float4(r[0].z, r[1].z, r[2].z, r[3].z);
        *(float4*)&Qt[e0 + 3][m0] = make_float4(r[0].w, r[1].w, r[2].w, r[3].w);
    }

    float m_[2]  = {-INFINITY, -INFINITY};
    float l_[2]  = {0.f, 0.f};
    float acc[2][4] = {{0.f, 0.f, 0.f, 0.f}, {0.f, 0.f, 0.f, 0.f}};

    const int c0 = (tid & 15) * 4;
    const int e0 = (tid >> 4) * 4;
    const float LOG2E = 1.4426950408889634f;

    for (int j = 0; j < nk; ++j) {
        // -- global loads (registers only) --
        float4 kr[4];
#pragma unroll
        for (int i = 0; i < 4; ++i)
            kr[i] = *(const float4*)&k[base + (size_t)(j * 64 + c0 + i) * HS + e0];
        float4 vr[4];
#pragma unroll
        for (int t = 0; t < 4; ++t) {
            int idx = tid + t * 256;
            vr[t] = *(const float4*)&v[base + (size_t)(j * 64 + (idx >> 4)) * HS + (idx & 15) * 4];
        }
        __syncthreads();   // prior tile's PV (Vs/Ps reads) done
        *(float4*)&Kt[e0 + 0][c0] = make_float4(kr[0].x, kr[1].x, kr[2].x, kr[3].x);
        *(float4*)&Kt[e0 + 1][c0] = make_float4(kr[0].y, kr[1].y, kr[2].y, kr[3].y);
        *(float4*)&Kt[e0 + 2][c0] = make_float4(kr[0].z, kr[1].z, kr[2].z, kr[3].z);
        *(float4*)&Kt[e0 + 3][c0] = make_float4(kr[0].w, kr[1].w, kr[2].w, kr[3].w);
#pragma unroll
        for (int t = 0; t < 4; ++t) {
            int idx = tid + t * 256;
            *(float4*)&Vs[idx >> 4][(idx & 15) * 4] = vr[t];
        }
        __syncthreads();

        // -- S = (Q/8) K^T : 2x4 per thread --
        float s[2][4] = {{0.f, 0.f, 0.f, 0.f}, {0.f, 0.f, 0.f, 0.f}};
#pragma unroll 16
        for (int e = 0; e < 64; ++e) {
            float2 qv = *(const float2*)&Qt[e][2 * a];
            float4 kv = *(const float4*)&Kt[e][4 * b];
            float qa[2] = {qv.x, qv.y};
            float ka[4] = {kv.x, kv.y, kv.z, kv.w};
#pragma unroll
            for (int rr = 0; rr < 2; ++rr)
#pragma unroll
                for (int cc = 0; cc < 4; ++cc)
                    s[rr][cc] = fmaf(qa[rr], ka[cc], s[rr][cc]);
        }
        // -- causal mask (only possible on final tile) --
        if (j == nk - 1) {
            int lim = qrow0 - j * 64;   // mask where c > r + lim
#pragma unroll
            for (int rr = 0; rr < 2; ++rr)
#pragma unroll
                for (int cc = 0; cc < 4; ++cc)
                    if (4 * b + cc > 2 * a + rr + lim) s[rr][cc] = -INFINITY;
        }
        // -- online softmax (16-lane shuffle reduce over col groups) --
#pragma unroll
        for (int rr = 0; rr < 2; ++rr) {
            float pm = fmaxf(fmaxf(s[rr][0], s[rr][1]), fmaxf(s[rr][2], s[rr][3]));
            pm = fmaxf(pm, __shfl_xor(pm, 1));
            pm = fmaxf(pm, __shfl_xor(pm, 2));
            pm = fmaxf(pm, __shfl_xor(pm, 4));
            pm = fmaxf(pm, __shfl_xor(pm, 8));
            float mnew = fmaxf(m_[rr], pm);
            float sc = exp2f((m_[rr] - mnew) * LOG2E);
            m_[rr] = mnew;
            float p[4], rs = 0.f;
#pragma unroll
            for (int cc = 0; cc < 4; ++cc) {
                p[cc] = exp2f((s[rr][cc] - mnew) * LOG2E);
                rs += p[cc];
            }
            rs += __shfl_xor(rs, 1);
            rs += __shfl_xor(rs, 2);
            rs += __shfl_xor(rs, 4);
            rs += __shfl_xor(rs, 8);
            l_[rr] = l_[rr] * sc + rs;
#pragma unroll
            for (int cc = 0; cc < 4; ++cc) {
                acc[rr][cc] *= sc;
                Ps[4 * b + cc][2 * a + rr] = p[cc];
            }
        }
        __syncthreads();   // Ps visible

        // -- O += P V --
#pragma unroll 16
        for (int c = 0; c < 64; ++c) {
            float2 pv = *(const float2*)&Ps[c][2 * a];
            float4 vv = *(const float4*)&Vs[c][4 * b];
            float pa[2] = {pv.x, pv.y};
            float va[4] = {vv.x, vv.y, vv.z, vv.w};
#pragma unroll
            for (int rr = 0; rr < 2; ++rr)
#pragma unroll
                for (int cc = 0; cc < 4; ++cc)
                    acc[rr][cc] = fmaf(pa[rr], va[cc], acc[rr][cc]);
        }
    }

    // -- normalize + write --
#pragma unroll
    for (int rr = 0; rr < 2; ++rr) {
        float inv = 1.0f / l_[rr];
        *(float4*)&out[base + (size_t)(qrow0 + 2 * a + rr) * HS + 4 * b] =
            make_float4(acc[rr][0] * inv, acc[rr][1] * inv,
                        acc[rr][2] * inv, acc[rr][3] * inv);
    }
}

extern "C" void kernel_launch(void* const* d_in, const int* in_sizes, int n_in,
                              void* d_out, int out_size, void* d_ws, size_t ws_size,
                              hipStream_t stream) {
    const float* x  = (const float*)d_in[0];
    const float* Wq = (const float*)d_in[1];
    const float* Wk = (const float*)d_in[2];
    const float* Wv = (const float*)d_in[3];
    float* out = (float*)d_out;

    float* qo = (float*)d_ws;                      // 3 x 16384 x 64 fp32 = 12.6 MB scratch
    float* ko = qo + (size_t)NROWS * HS;
    float* vo = ko + (size_t)NROWS * HS;

    qkv_kernel<<<NROWS / 64, 256, 0, stream>>>(x, Wq, Wk, Wv, qo, ko, vo);
    attn_kernel<<<NB * (SEQ / 32), 256, 0, stream>>>(qo, ko, vo, out);
}

// Round 4
// 238.942 us; speedup vs baseline: 1.4994x; 1.4994x over previous
//
#include <hip/hip_runtime.h>
#include <math.h>

#define EMB 768
#define HS 64
#define SEQ 2048
#define NB 8
#define NROWS (NB * SEQ)
#define LOG2E 1.4426950408889634f

typedef __attribute__((ext_vector_type(8))) short bf16x8;
typedef __attribute__((ext_vector_type(4))) float f32x4;
typedef unsigned short u16;

__device__ __forceinline__ u16 f2bf(float f) {
    unsigned u = __builtin_bit_cast(unsigned, f);
    return (u16)((u + 0x7fffu + ((u >> 16) & 1u)) >> 16);
}
__device__ __forceinline__ float bf2f(u16 h) {
    unsigned u = ((unsigned)h) << 16;
    return __builtin_bit_cast(float, u);
}

// ws layout (u16 units)
#define MATU ((size_t)NROWS * HS)        // 1048576 shorts per matrix image
#define WT2U ((size_t)12 * 24 * 64 * 8)  // 147456 shorts

// ---------------- Kernel 0: W -> fragment-tiled bf16 hi/lo ----------------
// Wt2[nt(12)][kk(24)][lane(64)][8] ; value = Wmat[k][(nt&3)*16 + (l&15)],
// k = kk*32 + (l>>4)*8 + jj ; mat = nt>>2 (0=Q scaled by 0.125, 1=K, 2=V).
__global__ __launch_bounds__(256) void prep_w(
    const float* __restrict__ Wq, const float* __restrict__ Wk,
    const float* __restrict__ Wv, u16* __restrict__ Whi, u16* __restrict__ Wlo)
{
    int fid = blockIdx.x * 256 + threadIdx.x;       // 0..18431
    int l = fid & 63, rest = fid >> 6;
    int kk = rest % 24, nt = rest / 24;
    int mat = nt >> 2;
    const float* W = (mat == 0) ? Wq : (mat == 1) ? Wk : Wv;
    float scale = (mat == 0) ? 0.125f : 1.0f;
    int col = (nt & 3) * 16 + (l & 15);
    int k0 = kk * 32 + (l >> 4) * 8;
    u16 hi[8], lo[8];
#pragma unroll
    for (int j = 0; j < 8; ++j) {
        float v = W[(size_t)(k0 + j) * HS + col] * scale;
        hi[j] = f2bf(v);
        lo[j] = f2bf(v - bf2f(hi[j]));
    }
    size_t o = (size_t)fid * 8;
#pragma unroll
    for (int j = 0; j < 8; ++j) { Whi[o + j] = hi[j]; Wlo[o + j] = lo[j]; }
}

// ---------------- Kernel 1: QKV projection via MFMA ----------------
// 256 blocks x 256 thr (4 waves). Wave w: rows blk*64 + w*16 .. +16, all 192 cols.
// Outputs fragment-tiled bf16 hi/lo:
//  Q2[qt16][kk2][64][8]   (A-frag layout for attention, pre-scaled by 1/8)
//  K2[b][j32][kt4][kk2][64][8]  (B-frag for QK^T)
//  V2[b][j32][ht4][kk2][64][8]  (B-frag for PV: V[k][h] with k in-lane)
#define LDP 72
__global__ __launch_bounds__(256) void qkv_mfma(
    const float* __restrict__ x,
    const u16* __restrict__ Whi, const u16* __restrict__ Wlo,
    u16* __restrict__ Q2hi, u16* __restrict__ Q2lo,
    u16* __restrict__ K2hi, u16* __restrict__ K2lo,
    u16* __restrict__ V2hi, u16* __restrict__ V2lo)
{
    __shared__ u16 ldsHi[64][LDP];
    __shared__ u16 ldsLo[64][LDP];

    const int tid = threadIdx.x;
    const int w = tid >> 6, l = tid & 63;
    const int t = l & 15, g = l >> 4;
    const int row0 = blockIdx.x * 64;
    const int myrow = row0 + w * 16 + t;

    f32x4 acc[12];
#pragma unroll
    for (int n = 0; n < 12; ++n) acc[n] = (f32x4){0.f, 0.f, 0.f, 0.f};

    const float* xrow = x + (size_t)myrow * EMB + g * 8;
#pragma unroll 1
    for (int kk = 0; kk < 24; ++kk) {
        float4 xa = *(const float4*)(xrow + kk * 32);
        float4 xb = *(const float4*)(xrow + kk * 32 + 4);
        float xv[8] = {xa.x, xa.y, xa.z, xa.w, xb.x, xb.y, xb.z, xb.w};
        bf16x8 ahi, alo;
#pragma unroll
        for (int j = 0; j < 8; ++j) {
            u16 h = f2bf(xv[j]);
            ahi[j] = (short)h;
            alo[j] = (short)f2bf(xv[j] - bf2f(h));
        }
#pragma unroll
        for (int nt = 0; nt < 12; ++nt) {
            size_t bo = ((size_t)(nt * 24 + kk) * 64 + l) * 8;
            bf16x8 bhi = *(const bf16x8*)(Whi + bo);
            bf16x8 blo = *(const bf16x8*)(Wlo + bo);
            acc[nt] = __builtin_amdgcn_mfma_f32_16x16x32_bf16(ahi, bhi, acc[nt], 0, 0, 0);
            acc[nt] = __builtin_amdgcn_mfma_f32_16x16x32_bf16(ahi, blo, acc[nt], 0, 0, 0);
            acc[nt] = __builtin_amdgcn_mfma_f32_16x16x32_bf16(alo, bhi, acc[nt], 0, 0, 0);
        }
    }

    const int b = row0 / SEQ;
    const int j64 = (row0 % SEQ) / 64;
    // epilogue: per matrix, stage 64x64 result in LDS then emit fragment-tiled
    for (int m3 = 0; m3 < 3; ++m3) {
        __syncthreads();   // previous matrix's LDS reads done
#pragma unroll
        for (int nt = 0; nt < 4; ++nt)
#pragma unroll
            for (int r = 0; r < 4; ++r) {
                float v = acc[m3 * 4 + nt][r];
                u16 h = f2bf(v);
                ldsHi[w * 16 + g * 4 + r][nt * 16 + t] = h;
                ldsLo[w * 16 + g * 4 + r][nt * 16 + t] = f2bf(v - bf2f(h));
            }
        __syncthreads();
        if (m3 == 0) {          // Q2: [qt16][kk][64][8]
#pragma unroll
            for (int rep = 0; rep < 2; ++rep) {
                int fid = tid + rep * 256;          // 0..511
                int fl = fid & 63;
                int qt = (fid >> 6) >> 1, fk = (fid >> 6) & 1;
                int rr = qt * 16 + (fl & 15), cc = fk * 32 + (fl >> 4) * 8;
                size_t o = (((size_t)(row0 / 16 + qt) * 2 + fk) * 64 + fl) * 8;
                *(bf16x8*)(Q2hi + o) = *(const bf16x8*)&ldsHi[rr][cc];
                *(bf16x8*)(Q2lo + o) = *(const bf16x8*)&ldsLo[rr][cc];
            }
        } else if (m3 == 1) {   // K2: [b][j][kt][kk][64][8]
#pragma unroll
            for (int rep = 0; rep < 2; ++rep) {
                int fid = tid + rep * 256;
                int fl = fid & 63;
                int kt = (fid >> 6) >> 1, fk = (fid >> 6) & 1;
                int rr = kt * 16 + (fl & 15), cc = fk * 32 + (fl >> 4) * 8;
                size_t o = ((((size_t)(b * 32 + j64) * 4 + kt) * 2 + fk) * 64 + fl) * 8;
                *(bf16x8*)(K2hi + o) = *(const bf16x8*)&ldsHi[rr][cc];
                *(bf16x8*)(K2lo + o) = *(const bf16x8*)&ldsLo[rr][cc];
            }
        } else {                // V2: transpose gather: value = V[k][h]
#pragma unroll
            for (int rep = 0; rep < 2; ++rep) {
                int fid = tid + rep * 256;
                int fl = fid & 63;
                int ht = (fid >> 6) >> 1, fk = (fid >> 6) & 1;
                int hcol = ht * 16 + (fl & 15);
                int krow = fk * 32 + (fl >> 4) * 8;
                bf16x8 vh, vl;
#pragma unroll
                for (int j = 0; j < 8; ++j) {
                    vh[j] = (short)ldsHi[krow + j][hcol];
                    vl[j] = (short)ldsLo[krow + j][hcol];
                }
                size_t o = ((((size_t)(b * 32 + j64) * 4 + ht) * 2 + fk) * 64 + fl) * 8;
                *(bf16x8*)(V2hi + o) = vh;
                *(bf16x8*)(V2lo + o) = vl;
            }
        }
    }
}

// ---------------- Kernel 2: causal flash attention via MFMA ----------------
// 512 blocks x 4 waves. BQ=32; wave w handles k-tiles j = w, w+4, ...; merge at end.
#define PSTR 80
__global__ __launch_bounds__(256, 2) void attn_mfma(
    const u16* __restrict__ Q2hi, const u16* __restrict__ Q2lo,
    const u16* __restrict__ K2hi, const u16* __restrict__ K2lo,
    const u16* __restrict__ V2hi, const u16* __restrict__ V2lo,
    float* __restrict__ out)
{
    __shared__ float Om[4][32][64];     // 32 KB
    __shared__ float Mlm[4][32];
    __shared__ float Mll[4][32];
    __shared__ u16 Phi[4][32][PSTR];    // 20 KB
    __shared__ u16 Plo[4][32][PSTR];    // 20 KB

    const int tid = threadIdx.x;
    const int w = tid >> 6, l = tid & 63;
    const int t = l & 15, g = l >> 4;
    const int bid = blockIdx.x;
    const int batch = bid & 7;
    const int qi = 63 - (bid >> 3);
    const int nk = (qi >> 1) + 1;
    const int qrow0 = qi * 32;

    // Q fragments (pre-scaled by 1/8 at projection time)
    bf16x8 qhi[2][2], qlo[2][2];
    const size_t qt0 = (size_t)batch * 128 + qi * 2;
#pragma unroll
    for (int m = 0; m < 2; ++m)
#pragma unroll
        for (int kk = 0; kk < 2; ++kk) {
            size_t o = (((qt0 + m) * 2 + kk) * 64 + l) * 8;
            qhi[m][kk] = *(const bf16x8*)(Q2hi + o);
            qlo[m][kk] = *(const bf16x8*)(Q2lo + o);
        }

    f32x4 o_[2][4];
#pragma unroll
    for (int m = 0; m < 2; ++m)
#pragma unroll
        for (int h = 0; h < 4; ++h) o_[m][h] = (f32x4){0.f, 0.f, 0.f, 0.f};
    float m_[2][4], l_[2][4];
#pragma unroll
    for (int m = 0; m < 2; ++m)
#pragma unroll
        for (int r = 0; r < 4; ++r) { m_[m][r] = -__builtin_huge_valf(); l_[m][r] = 0.f; }

    for (int j = w; j < nk; j += 4) {
        const size_t kb = (size_t)batch * 32 + j;
        // ---- S = Q K^T ----
        f32x4 s[2][4];
#pragma unroll
        for (int kt = 0; kt < 4; ++kt) {
            size_t o0 = (((kb * 4 + kt) * 2 + 0) * 64 + l) * 8;
            size_t o1 = (((kb * 4 + kt) * 2 + 1) * 64 + l) * 8;
            bf16x8 kh0 = *(const bf16x8*)(K2hi + o0);
            bf16x8 kh1 = *(const bf16x8*)(K2hi + o1);
            bf16x8 kl0 = *(const bf16x8*)(K2lo + o0);
            bf16x8 kl1 = *(const bf16x8*)(K2lo + o1);
#pragma unroll
            for (int m = 0; m < 2; ++m) {
                f32x4 sv = (f32x4){0.f, 0.f, 0.f, 0.f};
                sv = __builtin_amdgcn_mfma_f32_16x16x32_bf16(qhi[m][0], kh0, sv, 0, 0, 0);
                sv = __builtin_amdgcn_mfma_f32_16x16x32_bf16(qhi[m][1], kh1, sv, 0, 0, 0);
                sv = __builtin_amdgcn_mfma_f32_16x16x32_bf16(qhi[m][0], kl0, sv, 0, 0, 0);
                sv = __builtin_amdgcn_mfma_f32_16x16x32_bf16(qhi[m][1], kl1, sv, 0, 0, 0);
                sv = __builtin_amdgcn_mfma_f32_16x16x32_bf16(qlo[m][0], kh0, sv, 0, 0, 0);
                sv = __builtin_amdgcn_mfma_f32_16x16x32_bf16(qlo[m][1], kh1, sv, 0, 0, 0);
                s[m][kt] = sv;
            }
        }
        // ---- causal mask (diagonal tile only) ----
        if (j == nk - 1) {
            const int kbase = j * 64;
#pragma unroll
            for (int m = 0; m < 2; ++m)
#pragma unroll
                for (int kt = 0; kt < 4; ++kt)
#pragma unroll
                    for (int r = 0; r < 4; ++r)
                        if (kbase + kt * 16 + t > qrow0 + m * 16 + g * 4 + r)
                            s[m][kt][r] = -__builtin_huge_valf();
        }
        // ---- online softmax (rows owned per (m,r), 16-lane shfl reduce) ----
#pragma unroll
        for (int m = 0; m < 2; ++m)
#pragma unroll
            for (int r = 0; r < 4; ++r) {
                float pm = fmaxf(fmaxf(s[m][0][r], s[m][1][r]), fmaxf(s[m][2][r], s[m][3][r]));
                pm = fmaxf(pm, __shfl_xor(pm, 1));
                pm = fmaxf(pm, __shfl_xor(pm, 2));
                pm = fmaxf(pm, __shfl_xor(pm, 4));
                pm = fmaxf(pm, __shfl_xor(pm, 8));
                float mn = fmaxf(m_[m][r], pm);
                float sc = exp2f((m_[m][r] - mn) * LOG2E);
                m_[m][r] = mn;
                float ps[4], rs = 0.f;
#pragma unroll
                for (int kt = 0; kt < 4; ++kt) {
                    ps[kt] = exp2f((s[m][kt][r] - mn) * LOG2E);
                    rs += ps[kt];
                }
                rs += __shfl_xor(rs, 1);
                rs += __shfl_xor(rs, 2);
                rs += __shfl_xor(rs, 4);
                rs += __shfl_xor(rs, 8);
                l_[m][r] = l_[m][r] * sc + rs;
#pragma unroll
                for (int h = 0; h < 4; ++h) o_[m][h][r] *= sc;
                int prow = m * 16 + g * 4 + r;
#pragma unroll
                for (int kt = 0; kt < 4; ++kt) {
                    u16 ph = f2bf(ps[kt]);
                    Phi[w][prow][kt * 16 + t] = ph;
                    Plo[w][prow][kt * 16 + t] = f2bf(ps[kt] - bf2f(ph));
                }
            }
        // ---- P fragments (same-wave LDS roundtrip; compiler inserts lgkmcnt) ----
        bf16x8 pah[2][2], pal[2][2];
#pragma unroll
        for (int m = 0; m < 2; ++m)
#pragma unroll
            for (int kk = 0; kk < 2; ++kk) {
                pah[m][kk] = *(const bf16x8*)&Phi[w][m * 16 + t][kk * 32 + g * 8];
                pal[m][kk] = *(const bf16x8*)&Plo[w][m * 16 + t][kk * 32 + g * 8];
            }
        // ---- O += P V ----
#pragma unroll
        for (int ht = 0; ht < 4; ++ht) {
            size_t o0 = (((kb * 4 + ht) * 2 + 0) * 64 + l) * 8;
            size_t o1 = (((kb * 4 + ht) * 2 + 1) * 64 + l) * 8;
            bf16x8 vh0 = *(const bf16x8*)(V2hi + o0);
            bf16x8 vh1 = *(const bf16x8*)(V2hi + o1);
            bf16x8 vl0 = *(const bf16x8*)(V2lo + o0);
            bf16x8 vl1 = *(const bf16x8*)(V2lo + o1);
#pragma unroll
            for (int m = 0; m < 2; ++m) {
                f32x4 ov = o_[m][ht];
                ov = __builtin_amdgcn_mfma_f32_16x16x32_bf16(pah[m][0], vh0, ov, 0, 0, 0);
                ov = __builtin_amdgcn_mfma_f32_16x16x32_bf16(pah[m][1], vh1, ov, 0, 0, 0);
                ov = __builtin_amdgcn_mfma_f32_16x16x32_bf16(pah[m][0], vl0, ov, 0, 0, 0);
                ov = __builtin_amdgcn_mfma_f32_16x16x32_bf16(pah[m][1], vl1, ov, 0, 0, 0);
                ov = __builtin_amdgcn_mfma_f32_16x16x32_bf16(pal[m][0], vh0, ov, 0, 0, 0);
                ov = __builtin_amdgcn_mfma_f32_16x16x32_bf16(pal[m][1], vh1, ov, 0, 0, 0);
                o_[m][ht] = ov;
            }
        }
    }

    // ---- merge the 4 wave-partials ----
#pragma unroll
    for (int m = 0; m < 2; ++m)
#pragma unroll
        for (int ht = 0; ht < 4; ++ht)
#pragma unroll
            for (int r = 0; r < 4; ++r)
                Om[w][m * 16 + g * 4 + r][ht * 16 + t] = o_[m][ht][r];
    if (t == 0) {
#pragma unroll
        for (int m = 0; m < 2; ++m)
#pragma unroll
            for (int r = 0; r < 4; ++r) {
                Mlm[w][m * 16 + g * 4 + r] = m_[m][r];
                Mll[w][m * 16 + g * 4 + r] = l_[m][r];
            }
    }
    __syncthreads();
    {
        int row = tid >> 3;
        int hb = (tid & 7) * 8;
        float M = -__builtin_huge_valf();
#pragma unroll
        for (int ww = 0; ww < 4; ++ww) M = fmaxf(M, Mlm[ww][row]);
        float sc[4], lsum = 0.f;
#pragma unroll
        for (int ww = 0; ww < 4; ++ww) {
            sc[ww] = exp2f((Mlm[ww][row] - M) * LOG2E);
            lsum += Mll[ww][row] * sc[ww];
        }
        float inv = 1.0f / lsum;
        size_t ob = ((size_t)batch * SEQ + qrow0 + row) * HS + hb;
#pragma unroll
        for (int hh = 0; hh < 8; ++hh) {
            float v = Om[0][row][hb + hh] * sc[0] + Om[1][row][hb + hh] * sc[1]
                    + Om[2][row][hb + hh] * sc[2] + Om[3][row][hb + hh] * sc[3];
            out[ob + hh] = v * inv;
        }
    }
}

extern "C" void kernel_launch(void* const* d_in, const int* in_sizes, int n_in,
                              void* d_out, int out_size, void* d_ws, size_t ws_size,
                              hipStream_t stream) {
    const float* x  = (const float*)d_in[0];
    const float* Wq = (const float*)d_in[1];
    const float* Wk = (const float*)d_in[2];
    const float* Wv = (const float*)d_in[3];
    float* out = (float*)d_out;

    u16* base = (u16*)d_ws;
    u16* Q2hi = base + 0 * MATU;
    u16* Q2lo = base + 1 * MATU;
    u16* K2hi = base + 2 * MATU;
    u16* K2lo = base + 3 * MATU;
    u16* V2hi = base + 4 * MATU;
    u16* V2lo = base + 5 * MATU;
    u16* Whi  = base + 6 * MATU;
    u16* Wlo  = Whi + WT2U;

    prep_w<<<72, 256, 0, stream>>>(Wq, Wk, Wv, Whi, Wlo);
    qkv_mfma<<<NROWS / 64, 256, 0, stream>>>(x, Whi, Wlo, Q2hi, Q2lo, K2hi, K2lo, V2hi, V2lo);
    attn_mfma<<<NB * (SEQ / 32), 256, 0, stream>>>(Q2hi, Q2lo, K2hi, K2lo, V2hi, V2lo, out);
}

// Round 7
// 143.242 us; speedup vs baseline: 2.5011x; 1.6681x over previous
//
#include <hip/hip_runtime.h>
#include <math.h>

#define EMB 768
#define HS 64
#define SEQ 2048
#define NB 8
#define NROWS (NB * SEQ)
#define LOG2E 1.4426950408889634f

typedef __attribute__((ext_vector_type(8))) short bf16x8;
typedef __attribute__((ext_vector_type(4))) float f32x4;
typedef unsigned short u16;

__device__ __forceinline__ u16 f2bf(float f) {
    unsigned u = __builtin_bit_cast(unsigned, f);
    return (u16)((u + 0x7fffu + ((u >> 16) & 1u)) >> 16);
}
__device__ __forceinline__ float bf2f(u16 h) {
    unsigned u = ((unsigned)h) << 16;
    return __builtin_bit_cast(float, u);
}

typedef __attribute__((address_space(1))) const unsigned GU;
typedef __attribute__((address_space(3))) unsigned LU;
__device__ __forceinline__ void gl16(const void* g, void* s) {
    __builtin_amdgcn_global_load_lds((GU*)g, (LU*)s, 16, 0, 0);
}

// ws layout (u16 units)
#define MATU ((size_t)NROWS * HS)        // 1048576 shorts per frag image
#define WT2U ((size_t)12 * 24 * 64 * 8)  // 147456 shorts

// ---------------- Kernel 0: W -> fragment-tiled bf16 hi/lo ----------------
// Wt2[nt(12)][kk(24)][lane(64)][8] ; value = Wmat[k][(nt&3)*16 + (l&15)],
// k = kk*32 + (l>>4)*8 + jj ; mat = nt>>2 (0=Q scaled by 0.125, 1=K, 2=V).
__global__ __launch_bounds__(256) void prep_w(
    const float* __restrict__ Wq, const float* __restrict__ Wk,
    const float* __restrict__ Wv, u16* __restrict__ Whi, u16* __restrict__ Wlo)
{
    int fid = blockIdx.x * 256 + threadIdx.x;       // 0..18431
    int l = fid & 63, rest = fid >> 6;
    int kk = rest % 24, nt = rest / 24;
    int mat = nt >> 2;
    const float* W = (mat == 0) ? Wq : (mat == 1) ? Wk : Wv;
    float scale = (mat == 0) ? 0.125f : 1.0f;
    int col = (nt & 3) * 16 + (l & 15);
    int k0 = kk * 32 + (l >> 4) * 8;
    u16 hi[8], lo[8];
#pragma unroll
    for (int j = 0; j < 8; ++j) {
        float v = W[(size_t)(k0 + j) * HS + col] * scale;
        hi[j] = f2bf(v);
        lo[j] = f2bf(v - bf2f(hi[j]));
    }
    size_t o = (size_t)fid * 8;
#pragma unroll
    for (int j = 0; j < 8; ++j) { Whi[o + j] = hi[j]; Wlo[o + j] = lo[j]; }
}

// ---------------- Kernel 1: QKV projection via MFMA ----------------
// 768 blocks (3 per CU): block = 64 x-rows  x  ONE matrix (mat = bi%3).
// x staged fp32 via global_load_lds with 16B-unit XOR swizzle (rule #21:
// linear LDS dest + inverse-swizzled global src + swizzled read).
// W fragments staged once per block in LDS, shared by all 4 waves.
// Q,K: 3-term hi/lo split MFMA. V: single-term (PV tolerates bf16 V).
__global__ __launch_bounds__(256) void qkv_mfma(
    const float* __restrict__ x,
    const u16* __restrict__ Whi, const u16* __restrict__ Wlo,
    u16* __restrict__ Q2hi, u16* __restrict__ Q2lo,
    u16* __restrict__ K2hi, u16* __restrict__ K2lo,
    u16* __restrict__ V2hi)
{
    __shared__ float xbuf[2][64][32];     // 16 KB (double-buffered x tile)
    __shared__ u16 wbufH[2][4][64][8];    // 8 KB
    __shared__ u16 wbufL[2][4][64][8];    // 8 KB
    __shared__ u16 ldsHi[64][72];         // epilogue staging
    __shared__ u16 ldsLo[64][72];

    const int tid = threadIdx.x;
    const int w = tid >> 6, l = tid & 63;
    const int t = l & 15, g = l >> 4;
    const int bi = blockIdx.x;
    const int mat = bi % 3;               // 0=Q 1=K 2=V
    const int rg = bi / 3;                // 0..255
    const int row0 = rg * 64;

    // staging sources (per-lane). LDS dest is linear: wave w lane l -> +l*16B.
    // row = i*32 + w*8 + (l>>3); physical 16B-unit = l&7; logical unit = (l&7)^(row&7).
    const int srow = w * 8 + (l >> 3);
    const int ulog = (l & 7) ^ (l >> 3);  // (row&7) == (l>>3) since w*8%8==0
    const float* gx0 = x + (size_t)(row0 + srow) * EMB + ulog * 4;
    const float* gx1 = gx0 + (size_t)32 * EMB;
    const u16* gwH = Whi + ((size_t)(mat * 4 + w) * 24) * 512 + (size_t)l * 8;
    const u16* gwL = Wlo + ((size_t)(mat * 4 + w) * 24) * 512 + (size_t)l * 8;

    f32x4 acc[4];
#pragma unroll
    for (int n = 0; n < 4; ++n) acc[n] = (f32x4){0.f, 0.f, 0.f, 0.f};

#define STAGE(buf, kk)                                                         \
    do {                                                                       \
        gl16(gx0 + (kk) * 32, &xbuf[buf][w * 8][0]);                           \
        gl16(gx1 + (kk) * 32, &xbuf[buf][32 + w * 8][0]);                      \
        gl16(gwH + (size_t)(kk) * 512, &wbufH[buf][w][0][0]);                  \
        if (mat != 2) gl16(gwL + (size_t)(kk) * 512, &wbufL[buf][w][0][0]);    \
    } while (0)

    STAGE(0, 0);
    __syncthreads();

    const int rr = w * 16 + t;            // this lane's A-row
    const int sw = t & 7;                 // its swizzle key
    for (int kk = 0; kk < 24; ++kk) {
        const int cur = kk & 1;
        if (kk < 23) STAGE(cur ^ 1, kk + 1);     // flies under this tile's compute
        // swizzled fp32 x reads (conflict-free b128 per 8-lane group)
        float4 a0 = *(const float4*)&xbuf[cur][rr][((2 * g + 0) ^ sw) * 4];
        float4 a1 = *(const float4*)&xbuf[cur][rr][((2 * g + 1) ^ sw) * 4];
        float xv[8] = {a0.x, a0.y, a0.z, a0.w, a1.x, a1.y, a1.z, a1.w};
        bf16x8 ahi, alo;
#pragma unroll
        for (int j = 0; j < 8; ++j) {
            u16 h = f2bf(xv[j]);
            ahi[j] = (short)h;
            if (mat != 2) alo[j] = (short)f2bf(xv[j] - bf2f(h));
        }
        if (mat != 2) {
#pragma unroll
            for (int nt = 0; nt < 4; ++nt) {
                bf16x8 bhi = *(const bf16x8*)&wbufH[cur][nt][l][0];
                bf16x8 blo = *(const bf16x8*)&wbufL[cur][nt][l][0];
                acc[nt] = __builtin_amdgcn_mfma_f32_16x16x32_bf16(ahi, bhi, acc[nt], 0, 0, 0);
                acc[nt] = __builtin_amdgcn_mfma_f32_16x16x32_bf16(ahi, blo, acc[nt], 0, 0, 0);
                acc[nt] = __builtin_amdgcn_mfma_f32_16x16x32_bf16(alo, bhi, acc[nt], 0, 0, 0);
            }
        } else {
#pragma unroll
            for (int nt = 0; nt < 4; ++nt) {
                bf16x8 bhi = *(const bf16x8*)&wbufH[cur][nt][l][0];
                acc[nt] = __builtin_amdgcn_mfma_f32_16x16x32_bf16(ahi, bhi, acc[nt], 0, 0, 0);
            }
        }
        __syncthreads();   // all reads of buf[cur] done; stage(kk+1) drained
    }
#undef STAGE

    // ---- epilogue: stage D-frags, emit fragment-tiled ----
#pragma unroll
    for (int nt = 0; nt < 4; ++nt)
#pragma unroll
        for (int r = 0; r < 4; ++r) {
            float v = acc[nt][r];
            u16 h = f2bf(v);
            ldsHi[w * 16 + g * 4 + r][nt * 16 + t] = h;
            if (mat != 2) ldsLo[w * 16 + g * 4 + r][nt * 16 + t] = f2bf(v - bf2f(h));
        }
    __syncthreads();

    const int b = row0 / SEQ, j64 = (row0 % SEQ) / 64;
    if (mat == 0) {          // Q2[qt][kkf][64][8] hi+lo
#pragma unroll
        for (int rep = 0; rep < 2; ++rep) {
            int fid = tid + rep * 256;
            int fl = fid & 63;
            int qt = (fid >> 6) >> 1, fk = (fid >> 6) & 1;
            int r2 = qt * 16 + (fl & 15), cc = fk * 32 + (fl >> 4) * 8;
            size_t o = (((size_t)(row0 / 16 + qt) * 2 + fk) * 64 + fl) * 8;
            *(bf16x8*)(Q2hi + o) = *(const bf16x8*)&ldsHi[r2][cc];
            *(bf16x8*)(Q2lo + o) = *(const bf16x8*)&ldsLo[r2][cc];
        }
    } else if (mat == 1) {   // K2[b][j][kt][kkf][64][8] hi+lo
#pragma unroll
        for (int rep = 0; rep < 2; ++rep) {
            int fid = tid + rep * 256;
            int fl = fid & 63;
            int kt = (fid >> 6) >> 1, fk = (fid >> 6) & 1;
            int r2 = kt * 16 + (fl & 15), cc = fk * 32 + (fl >> 4) * 8;
            size_t o = ((((size_t)(b * 32 + j64) * 4 + kt) * 2 + fk) * 64 + fl) * 8;
            *(bf16x8*)(K2hi + o) = *(const bf16x8*)&ldsHi[r2][cc];
            *(bf16x8*)(K2lo + o) = *(const bf16x8*)&ldsLo[r2][cc];
        }
    } else {                 // V2[b][j][ht][kkf][64][8] hi only (transpose gather)
#pragma unroll
        for (int rep = 0; rep < 2; ++rep) {
            int fid = tid + rep * 256;
            int fl = fid & 63;
            int ht = (fid >> 6) >> 1, fk = (fid >> 6) & 1;
            int hcol = ht * 16 + (fl & 15);
            int krow = fk * 32 + (fl >> 4) * 8;
            bf16x8 vh;
#pragma unroll
            for (int j = 0; j < 8; ++j) vh[j] = (short)ldsHi[krow + j][hcol];
            size_t o = ((((size_t)(b * 32 + j64) * 4 + ht) * 2 + fk) * 64 + fl) * 8;
            *(bf16x8*)(V2hi + o) = vh;
        }
    }
}

// ---------------- Kernel 2: causal flash attention via MFMA ----------------
// 1024 blocks x 4 waves (BQ=16). Wave w: k-tiles j = w, w+4, ...; merge at end.
// No barriers in the j-loop. QK = 6-MFMA hi/lo split; PV = single bf16.
#define PSTR 80
__global__ __launch_bounds__(256, 3) void attn_mfma(
    const u16* __restrict__ Q2hi, const u16* __restrict__ Q2lo,
    const u16* __restrict__ K2hi, const u16* __restrict__ K2lo,
    const u16* __restrict__ V2hi, float* __restrict__ out)
{
    __shared__ float Om[4][16][64];      // 16 KB; Phi aliases this during the loop
    __shared__ float Mlm[4][16];
    __shared__ float Mll[4][16];
    u16* Phi = (u16*)&Om[0][0][0];       // [4][16][PSTR] = 10 KB < 16 KB

    const int tid = threadIdx.x;
    const int w = tid >> 6, l = tid & 63;
    const int t = l & 15, g = l >> 4;
    const int bid = blockIdx.x;
    const int batch = bid & 7;
    const int qi = 127 - (bid >> 3);     // heavy q-tiles first
    const int nk = (qi >> 2) + 1;        // # 64-wide k-tiles
    const int qrow0 = qi * 16;

    // Q fragments (pre-scaled by 1/8 via Wq)
    bf16x8 qhi[2], qlo[2];
    const size_t qt = (size_t)batch * 128 + qi;
#pragma unroll
    for (int kkf = 0; kkf < 2; ++kkf) {
        size_t o = ((qt * 2 + kkf) * 64 + l) * 8;
        qhi[kkf] = *(const bf16x8*)(Q2hi + o);
        qlo[kkf] = *(const bf16x8*)(Q2lo + o);
    }

    f32x4 o_[4];
#pragma unroll
    for (int h = 0; h < 4; ++h) o_[h] = (f32x4){0.f, 0.f, 0.f, 0.f};
    float m_[4], l_[4];
#pragma unroll
    for (int r = 0; r < 4; ++r) { m_[r] = -__builtin_huge_valf(); l_[r] = 0.f; }

    for (int j = w; j < nk; j += 4) {
        const size_t jb = ((size_t)(batch * 32 + j)) * 4096;
        const u16* kH = K2hi + jb + (size_t)l * 8;
        const u16* kL = K2lo + jb + (size_t)l * 8;
        const u16* vH = V2hi + jb + (size_t)l * 8;
        // prefetch V early: latency hides under QK + softmax
        bf16x8 vf[4][2];
#pragma unroll
        for (int ht = 0; ht < 4; ++ht)
#pragma unroll
            for (int kkf = 0; kkf < 2; ++kkf)
                vf[ht][kkf] = *(const bf16x8*)(vH + ht * 1024 + kkf * 512);
        // ---- S = Q K^T ----
        f32x4 s[4];
#pragma unroll
        for (int kt = 0; kt < 4; ++kt) {
            bf16x8 kh0 = *(const bf16x8*)(kH + kt * 1024);
            bf16x8 kh1 = *(const bf16x8*)(kH + kt * 1024 + 512);
            bf16x8 kl0 = *(const bf16x8*)(kL + kt * 1024);
            bf16x8 kl1 = *(const bf16x8*)(kL + kt * 1024 + 512);
            f32x4 sv = (f32x4){0.f, 0.f, 0.f, 0.f};
            sv = __builtin_amdgcn_mfma_f32_16x16x32_bf16(qhi[0], kh0, sv, 0, 0, 0);
            sv = __builtin_amdgcn_mfma_f32_16x16x32_bf16(qhi[1], kh1, sv, 0, 0, 0);
            sv = __builtin_amdgcn_mfma_f32_16x16x32_bf16(qhi[0], kl0, sv, 0, 0, 0);
            sv = __builtin_amdgcn_mfma_f32_16x16x32_bf16(qhi[1], kl1, sv, 0, 0, 0);
            sv = __builtin_amdgcn_mfma_f32_16x16x32_bf16(qlo[0], kh0, sv, 0, 0, 0);
            sv = __builtin_amdgcn_mfma_f32_16x16x32_bf16(qlo[1], kh1, sv, 0, 0, 0);
            s[kt] = sv;
        }
        // ---- causal mask (diagonal tile only) ----
        if (j == nk - 1) {
#pragma unroll
            for (int kt = 0; kt < 4; ++kt)
#pragma unroll
                for (int r = 0; r < 4; ++r)
                    if (j * 64 + kt * 16 + t > qrow0 + g * 4 + r)
                        s[kt][r] = -__builtin_huge_valf();
        }
        // ---- online softmax (rows g*4+r; 16-lane shfl reduce over t) ----
#pragma unroll
        for (int r = 0; r < 4; ++r) {
            float pm = fmaxf(fmaxf(s[0][r], s[1][r]), fmaxf(s[2][r], s[3][r]));
            pm = fmaxf(pm, __shfl_xor(pm, 1));
            pm = fmaxf(pm, __shfl_xor(pm, 2));
            pm = fmaxf(pm, __shfl_xor(pm, 4));
            pm = fmaxf(pm, __shfl_xor(pm, 8));
            float mn = fmaxf(m_[r], pm);
            float sc = exp2f((m_[r] - mn) * LOG2E);
            m_[r] = mn;
            float ps[4], rs = 0.f;
#pragma unroll
            for (int kt = 0; kt < 4; ++kt) {
                ps[kt] = exp2f((s[kt][r] - mn) * LOG2E);
                rs += ps[kt];
            }
            rs += __shfl_xor(rs, 1);
            rs += __shfl_xor(rs, 2);
            rs += __shfl_xor(rs, 4);
            rs += __shfl_xor(rs, 8);
            l_[r] = l_[r] * sc + rs;
#pragma unroll
            for (int ht = 0; ht < 4; ++ht) o_[ht][r] *= sc;
            int prow = g * 4 + r;
#pragma unroll
            for (int kt = 0; kt < 4; ++kt)
                Phi[(w * 16 + prow) * PSTR + kt * 16 + t] = f2bf(ps[kt]);
        }
        // ---- P A-fragments (same-wave LDS roundtrip) ----
        bf16x8 pa[2];
#pragma unroll
        for (int kkf = 0; kkf < 2; ++kkf)
            pa[kkf] = *(const bf16x8*)&Phi[(w * 16 + t) * PSTR + kkf * 32 + g * 8];
        // ---- O += P V (single-precision bf16) ----
#pragma unroll
        for (int ht = 0; ht < 4; ++ht) {
            o_[ht] = __builtin_amdgcn_mfma_f32_16x16x32_bf16(pa[0], vf[ht][0], o_[ht], 0, 0, 0);
            o_[ht] = __builtin_amdgcn_mfma_f32_16x16x32_bf16(pa[1], vf[ht][1], o_[ht], 0, 0, 0);
        }
    }

    // ---- merge the 4 wave-partials (Phi dead from here; Om aliases it) ----
    __syncthreads();
#pragma unroll
    for (int ht = 0; ht < 4; ++ht)
#pragma unroll
        for (int r = 0; r < 4; ++r)
            Om[w][g * 4 + r][ht * 16 + t] = o_[ht][r];
    if (t == 0) {
#pragma unroll
        for (int r = 0; r < 4; ++r) {
            Mlm[w][g * 4 + r] = m_[r];
            Mll[w][g * 4 + r] = l_[r];
        }
    }
    __syncthreads();
    {
        int row = tid >> 4;
        int hc = (tid & 15) * 4;
        float M = fmaxf(fmaxf(Mlm[0][row], Mlm[1][row]), fmaxf(Mlm[2][row], Mlm[3][row]));
        float scw[4], lsum = 0.f;
#pragma unroll
        for (int ww = 0; ww < 4; ++ww) {
            scw[ww] = exp2f((Mlm[ww][row] - M) * LOG2E);
            lsum += Mll[ww][row] * scw[ww];
        }
        float inv = 1.0f / lsum;
        float4 o;
        o.x = (Om[0][row][hc + 0] * scw[0] + Om[1][row][hc + 0] * scw[1]
             + Om[2][row][hc + 0] * scw[2] + Om[3][row][hc + 0] * scw[3]) * inv;
        o.y = (Om[0][row][hc + 1] * scw[0] + Om[1][row][hc + 1] * scw[1]
             + Om[2][row][hc + 1] * scw[2] + Om[3][row][hc + 1] * scw[3]) * inv;
        o.z = (Om[0][row][hc + 2] * scw[0] + Om[1][row][hc + 2] * scw[1]
             + Om[2][row][hc + 2] * scw[2] + Om[3][row][hc + 2] * scw[3]) * inv;
        o.w = (Om[0][row][hc + 3] * scw[0] + Om[1][row][hc + 3] * scw[1]
             + Om[2][row][hc + 3] * scw[2] + Om[3][row][hc + 3] * scw[3]) * inv;
        *(float4*)&out[((size_t)batch * SEQ + qrow0 + row) * HS + hc] = o;
    }
}

extern "C" void kernel_launch(void* const* d_in, const int* in_sizes, int n_in,
                              void* d_out, int out_size, void* d_ws, size_t ws_size,
                              hipStream_t stream) {
    const float* x  = (const float*)d_in[0];
    const float* Wq = (const float*)d_in[1];
    const float* Wk = (const float*)d_in[2];
    const float* Wv = (const float*)d_in[3];
    float* out = (float*)d_out;

    u16* base = (u16*)d_ws;                  // ~11.1 MB total scratch
    u16* Q2hi = base + 0 * MATU;
    u16* Q2lo = base + 1 * MATU;
    u16* K2hi = base + 2 * MATU;
    u16* K2lo = base + 3 * MATU;
    u16* V2hi = base + 4 * MATU;
    u16* Whi  = base + 5 * MATU;
    u16* Wlo  = Whi + WT2U;

    prep_w<<<72, 256, 0, stream>>>(Wq, Wk, Wv, Whi, Wlo);
    qkv_mfma<<<768, 256, 0, stream>>>(x, Whi, Wlo, Q2hi, Q2lo, K2hi, K2lo, V2hi);
    attn_mfma<<<NB * (SEQ / 16), 256, 0, stream>>>(Q2hi, Q2lo, K2hi, K2lo, V2hi, out);
}

// Round 8
// 131.339 us; speedup vs baseline: 2.7278x; 1.0906x over previous
//
#include <hip/hip_runtime.h>
#include <math.h>

#define EMB 768
#define HS 64
#define SEQ 2048
#define NB 8
#define NROWS (NB * SEQ)
#define LOG2E 1.4426950408889634f

typedef __attribute__((ext_vector_type(8))) _Float16 f16x8;
typedef __attribute__((ext_vector_type(4))) float f32x4;
typedef unsigned short u16;

__device__ __forceinline__ u16 f2h(float f) {
    return __builtin_bit_cast(u16, (_Float16)f);
}

typedef __attribute__((address_space(1))) const unsigned GU;
typedef __attribute__((address_space(3))) unsigned LU;
__device__ __forceinline__ void gl16(const void* g, void* s) {
    __builtin_amdgcn_global_load_lds((GU*)g, (LU*)s, 16, 0, 0);
}

// ws layout (u16 units)
#define MATU ((size_t)NROWS * HS)        // 1048576 shorts per frag image
#define WT2U ((size_t)12 * 24 * 64 * 8)  // 147456 shorts

// ---------------- Kernel 0: W -> fragment-tiled fp16 ----------------
// Wt[nt(12)][kk(24)][lane(64)][8] ; value = Wmat[k][(nt&3)*16 + (l&15)],
// k = kk*32 + (l>>4)*8 + jj ; mat = nt>>2 (0=Q scaled by 0.125, 1=K, 2=V).
__global__ __launch_bounds__(256) void prep_w(
    const float* __restrict__ Wq, const float* __restrict__ Wk,
    const float* __restrict__ Wv, u16* __restrict__ Wh)
{
    int fid = blockIdx.x * 256 + threadIdx.x;       // 0..18431
    int l = fid & 63, rest = fid >> 6;
    int kk = rest % 24, nt = rest / 24;
    int mat = nt >> 2;
    const float* W = (mat == 0) ? Wq : (mat == 1) ? Wk : Wv;
    float scale = (mat == 0) ? 0.125f : 1.0f;
    int col = (nt & 3) * 16 + (l & 15);
    int k0 = kk * 32 + (l >> 4) * 8;
    size_t o = (size_t)fid * 8;
#pragma unroll
    for (int j = 0; j < 8; ++j)
        Wh[o + j] = f2h(W[(size_t)(k0 + j) * HS + col] * scale);
}

// ---------------- Kernel 1: QKV projection via MFMA (fp16) ----------------
// 768 blocks (3 per CU): block = 64 x-rows x ONE matrix (mat = bi%3).
// x staged fp32 via global_load_lds with 16B-unit XOR swizzle (rule #21).
// W fragments staged once per block in LDS, shared by all 4 waves.
__global__ __launch_bounds__(256) void qkv_mfma(
    const float* __restrict__ x, const u16* __restrict__ Wh,
    u16* __restrict__ Q2, u16* __restrict__ K2, u16* __restrict__ V2)
{
    __shared__ float xbuf[2][64][32];     // 16 KB (double-buffered x tile)
    __shared__ u16 wbuf[2][4][64][8];     // 8 KB
    __shared__ u16 ldsH[64][72];          // epilogue staging

    const int tid = threadIdx.x;
    const int w = tid >> 6, l = tid & 63;
    const int t = l & 15, g = l >> 4;
    const int bi = blockIdx.x;
    const int mat = bi % 3;               // 0=Q 1=K 2=V
    const int row0 = (bi / 3) * 64;

    // staging sources (per-lane). LDS dest linear: wave w lane l -> +l*16B.
    const int srow = w * 8 + (l >> 3);
    const int ulog = (l & 7) ^ (l >> 3);
    const float* gx0 = x + (size_t)(row0 + srow) * EMB + ulog * 4;
    const float* gx1 = gx0 + (size_t)32 * EMB;
    const u16* gw = Wh + ((size_t)(mat * 4 + w) * 24) * 512 + (size_t)l * 8;

    f32x4 acc[4];
#pragma unroll
    for (int n = 0; n < 4; ++n) acc[n] = (f32x4){0.f, 0.f, 0.f, 0.f};

#define STAGE(buf, kk)                                                \
    do {                                                              \
        gl16(gx0 + (kk) * 32, &xbuf[buf][w * 8][0]);                  \
        gl16(gx1 + (kk) * 32, &xbuf[buf][32 + w * 8][0]);             \
        gl16(gw + (size_t)(kk) * 512, &wbuf[buf][w][0][0]);           \
    } while (0)

    STAGE(0, 0);
    __syncthreads();

    const int rr = w * 16 + t;            // this lane's A-row
    const int sw = t & 7;                 // its swizzle key
    for (int kk = 0; kk < 24; ++kk) {
        const int cur = kk & 1;
        if (kk < 23) STAGE(cur ^ 1, kk + 1);     // flies under this tile's compute
        float4 a0 = *(const float4*)&xbuf[cur][rr][((2 * g + 0) ^ sw) * 4];
        float4 a1 = *(const float4*)&xbuf[cur][rr][((2 * g + 1) ^ sw) * 4];
        f16x8 a;
        a[0] = (_Float16)a0.x; a[1] = (_Float16)a0.y;
        a[2] = (_Float16)a0.z; a[3] = (_Float16)a0.w;
        a[4] = (_Float16)a1.x; a[5] = (_Float16)a1.y;
        a[6] = (_Float16)a1.z; a[7] = (_Float16)a1.w;
#pragma unroll
        for (int nt = 0; nt < 4; ++nt) {
            f16x8 b = *(const f16x8*)&wbuf[cur][nt][l][0];
            acc[nt] = __builtin_amdgcn_mfma_f32_16x16x32_f16(a, b, acc[nt], 0, 0, 0);
        }
        __syncthreads();   // all reads of buf[cur] done; stage(kk+1) drained
    }
#undef STAGE

    // ---- epilogue: stage D-frags as fp16, emit fragment-tiled ----
#pragma unroll
    for (int nt = 0; nt < 4; ++nt)
#pragma unroll
        for (int r = 0; r < 4; ++r)
            ldsH[w * 16 + g * 4 + r][nt * 16 + t] = f2h(acc[nt][r]);
    __syncthreads();

    const int b = row0 / SEQ, j64 = (row0 % SEQ) / 64;
    if (mat == 0) {          // Q2[qt][kkf][64][8]
#pragma unroll
        for (int rep = 0; rep < 2; ++rep) {
            int fid = tid + rep * 256;
            int fl = fid & 63;
            int qt = (fid >> 6) >> 1, fk = (fid >> 6) & 1;
            int r2 = qt * 16 + (fl & 15), cc = fk * 32 + (fl >> 4) * 8;
            size_t o = (((size_t)(row0 / 16 + qt) * 2 + fk) * 64 + fl) * 8;
            *(f16x8*)(Q2 + o) = *(const f16x8*)&ldsH[r2][cc];
        }
    } else if (mat == 1) {   // K2[b][j][kt][kkf][64][8]
#pragma unroll
        for (int rep = 0; rep < 2; ++rep) {
            int fid = tid + rep * 256;
            int fl = fid & 63;
            int kt = (fid >> 6) >> 1, fk = (fid >> 6) & 1;
            int r2 = kt * 16 + (fl & 15), cc = fk * 32 + (fl >> 4) * 8;
            size_t o = ((((size_t)(b * 32 + j64) * 4 + kt) * 2 + fk) * 64 + fl) * 8;
            *(f16x8*)(K2 + o) = *(const f16x8*)&ldsH[r2][cc];
        }
    } else {                 // V2[b][j][ht][kkf][64][8] (transpose gather)
#pragma unroll
        for (int rep = 0; rep < 2; ++rep) {
            int fid = tid + rep * 256;
            int fl = fid & 63;
            int ht = (fid >> 6) >> 1, fk = (fid >> 6) & 1;
            int hcol = ht * 16 + (fl & 15);
            int krow = fk * 32 + (fl >> 4) * 8;
            u16 vh[8];
#pragma unroll
            for (int j = 0; j < 8; ++j) vh[j] = ldsH[krow + j][hcol];
            size_t o = ((((size_t)(b * 32 + j64) * 4 + ht) * 2 + fk) * 64 + fl) * 8;
            *(f16x8*)(V2 + o) = *(const f16x8*)&vh[0];
        }
    }
}

// ---------------- Kernel 2: causal flash attention via MFMA (fp16) ----------------
// 1024 blocks x 4 waves (BQ=16). Wave w: k-tiles j = w, w+4, ...; merge at end.
// No barriers in the j-loop. QK 2 MFMA/kt-pair... 8 total; PV 8; all single fp16.
#define PSTR 80
__global__ __launch_bounds__(256, 3) void attn_mfma(
    const u16* __restrict__ Q2, const u16* __restrict__ K2,
    const u16* __restrict__ V2, float* __restrict__ out)
{
    __shared__ float Om[4][16][64];      // 16 KB; Phi aliases this during the loop
    __shared__ float Mlm[4][16];
    __shared__ float Mll[4][16];
    u16* Phi = (u16*)&Om[0][0][0];       // [4][16][PSTR] = 10 KB < 16 KB

    const int tid = threadIdx.x;
    const int w = tid >> 6, l = tid & 63;
    const int t = l & 15, g = l >> 4;
    const int bid = blockIdx.x;
    const int batch = bid & 7;
    const int qi = 127 - (bid >> 3);     // heavy q-tiles first
    const int nk = (qi >> 2) + 1;        // # 64-wide k-tiles
    const int qrow0 = qi * 16;

    // Q fragments (pre-scaled by 1/8 via Wq)
    f16x8 q[2];
    const size_t qt = (size_t)batch * 128 + qi;
#pragma unroll
    for (int kkf = 0; kkf < 2; ++kkf)
        q[kkf] = *(const f16x8*)(Q2 + ((qt * 2 + kkf) * 64 + l) * 8);

    f32x4 o_[4];
#pragma unroll
    for (int h = 0; h < 4; ++h) o_[h] = (f32x4){0.f, 0.f, 0.f, 0.f};
    float m_[4], l_[4];
#pragma unroll
    for (int r = 0; r < 4; ++r) { m_[r] = -__builtin_huge_valf(); l_[r] = 0.f; }

    for (int j = w; j < nk; j += 4) {
        const size_t jb = ((size_t)(batch * 32 + j)) * 4096;
        const u16* kP = K2 + jb + (size_t)l * 8;
        const u16* vP = V2 + jb + (size_t)l * 8;
        // prefetch V early: latency hides under QK + softmax
        f16x8 vf[4][2];
#pragma unroll
        for (int ht = 0; ht < 4; ++ht)
#pragma unroll
            for (int kkf = 0; kkf < 2; ++kkf)
                vf[ht][kkf] = *(const f16x8*)(vP + ht * 1024 + kkf * 512);
        // ---- S = Q K^T ----
        f32x4 s[4];
#pragma unroll
        for (int kt = 0; kt < 4; ++kt) {
            f16x8 k0 = *(const f16x8*)(kP + kt * 1024);
            f16x8 k1 = *(const f16x8*)(kP + kt * 1024 + 512);
            f32x4 sv = (f32x4){0.f, 0.f, 0.f, 0.f};
            sv = __builtin_amdgcn_mfma_f32_16x16x32_f16(q[0], k0, sv, 0, 0, 0);
            sv = __builtin_amdgcn_mfma_f32_16x16x32_f16(q[1], k1, sv, 0, 0, 0);
            s[kt] = sv;
        }
        // ---- causal mask (diagonal tile only) ----
        if (j == nk - 1) {
#pragma unroll
            for (int kt = 0; kt < 4; ++kt)
#pragma unroll
                for (int r = 0; r < 4; ++r)
                    if (j * 64 + kt * 16 + t > qrow0 + g * 4 + r)
                        s[kt][r] = -__builtin_huge_valf();
        }
        // ---- online softmax (rows g*4+r; 16-lane shfl reduce over t) ----
#pragma unroll
        for (int r = 0; r < 4; ++r) {
            float pm = fmaxf(fmaxf(s[0][r], s[1][r]), fmaxf(s[2][r], s[3][r]));
            pm = fmaxf(pm, __shfl_xor(pm, 1));
            pm = fmaxf(pm, __shfl_xor(pm, 2));
            pm = fmaxf(pm, __shfl_xor(pm, 4));
            pm = fmaxf(pm, __shfl_xor(pm, 8));
            float mn = fmaxf(m_[r], pm);
            float sc = exp2f((m_[r] - mn) * LOG2E);
            m_[r] = mn;
            float ps[4], rs = 0.f;
#pragma unroll
            for (int kt = 0; kt < 4; ++kt) {
                ps[kt] = exp2f((s[kt][r] - mn) * LOG2E);
                rs += ps[kt];
            }
            rs += __shfl_xor(rs, 1);
            rs += __shfl_xor(rs, 2);
            rs += __shfl_xor(rs, 4);
            rs += __shfl_xor(rs, 8);
            l_[r] = l_[r] * sc + rs;
#pragma unroll
            for (int ht = 0; ht < 4; ++ht) o_[ht][r] *= sc;
            int prow = g * 4 + r;
#pragma unroll
            for (int kt = 0; kt < 4; ++kt)
                Phi[(w * 16 + prow) * PSTR + kt * 16 + t] = f2h(ps[kt]);
        }
        // ---- P A-fragments (same-wave LDS roundtrip) ----
        f16x8 pa[2];
#pragma unroll
        for (int kkf = 0; kkf < 2; ++kkf)
            pa[kkf] = *(const f16x8*)&Phi[(w * 16 + t) * PSTR + kkf * 32 + g * 8];
        // ---- O += P V ----
#pragma unroll
        for (int ht = 0; ht < 4; ++ht) {
            o_[ht] = __builtin_amdgcn_mfma_f32_16x16x32_f16(pa[0], vf[ht][0], o_[ht], 0, 0, 0);
            o_[ht] = __builtin_amdgcn_mfma_f32_16x16x32_f16(pa[1], vf[ht][1], o_[ht], 0, 0, 0);
        }
    }

    // ---- merge the 4 wave-partials (Phi dead from here; Om aliases it) ----
    __syncthreads();
#pragma unroll
    for (int ht = 0; ht < 4; ++ht)
#pragma unroll
        for (int r = 0; r < 4; ++r)
            Om[w][g * 4 + r][ht * 16 + t] = o_[ht][r];
    if (t == 0) {
#pragma unroll
        for (int r = 0; r < 4; ++r) {
            Mlm[w][g * 4 + r] = m_[r];
            Mll[w][g * 4 + r] = l_[r];
        }
    }
    __syncthreads();
    {
        int row = tid >> 4;
        int hc = (tid & 15) * 4;
        float M = fmaxf(fmaxf(Mlm[0][row], Mlm[1][row]), fmaxf(Mlm[2][row], Mlm[3][row]));
        float scw[4], lsum = 0.f;
#pragma unroll
        for (int ww = 0; ww < 4; ++ww) {
            scw[ww] = exp2f((Mlm[ww][row] - M) * LOG2E);
            lsum += Mll[ww][row] * scw[ww];
        }
        float inv = 1.0f / lsum;
        float4 o;
        o.x = (Om[0][row][hc + 0] * scw[0] + Om[1][row][hc + 0] * scw[1]
             + Om[2][row][hc + 0] * scw[2] + Om[3][row][hc + 0] * scw[3]) * inv;
        o.y = (Om[0][row][hc + 1] * scw[0] + Om[1][row][hc + 1] * scw[1]
             + Om[2][row][hc + 1] * scw[2] + Om[3][row][hc + 1] * scw[3]) * inv;
        o.z = (Om[0][row][hc + 2] * scw[0] + Om[1][row][hc + 2] * scw[1]
             + Om[2][row][hc + 2] * scw[2] + Om[3][row][hc + 2] * scw[3]) * inv;
        o.w = (Om[0][row][hc + 3] * scw[0] + Om[1][row][hc + 3] * scw[1]
             + Om[2][row][hc + 3] * scw[2] + Om[3][row][hc + 3] * scw[3]) * inv;
        *(float4*)&out[((size_t)batch * SEQ + qrow0 + row) * HS + hc] = o;
    }
}

extern "C" void kernel_launch(void* const* d_in, const int* in_sizes, int n_in,
                              void* d_out, int out_size, void* d_ws, size_t ws_size,
                              hipStream_t stream) {
    const float* x  = (const float*)d_in[0];
    const float* Wq = (const float*)d_in[1];
    const float* Wk = (const float*)d_in[2];
    const float* Wv = (const float*)d_in[3];
    float* out = (float*)d_out;

    u16* base = (u16*)d_ws;                  // ~6.6 MB total scratch
    u16* Q2 = base + 0 * MATU;
    u16* K2 = base + 1 * MATU;
    u16* V2 = base + 2 * MATU;
    u16* Wh = base + 3 * MATU;

    prep_w<<<72, 256, 0, stream>>>(Wq, Wk, Wv, Wh);
    qkv_mfma<<<768, 256, 0, stream>>>(x, Wh, Q2, K2, V2);
    attn_mfma<<<NB * (SEQ / 16), 256, 0, stream>>>(Q2, K2, V2, out);
}